// Round 9
// baseline (499.754 us; speedup 1.0000x reference)
//
#include <hip/hip_runtime.h>
#include <hip/hip_bf16.h>
#include <cstdint>

typedef short short8 __attribute__((ext_vector_type(8)));
typedef float f32x4 __attribute__((ext_vector_type(4)));
typedef int   int4v __attribute__((ext_vector_type(4)));
typedef _Float16 fp16x8 __attribute__((ext_vector_type(8)));

using bf16 = __hip_bfloat16;

#define MFMA16(a, b, c) __builtin_amdgcn_mfma_f32_16x16x32_bf16((a), (b), (c), 0, 0, 0)
#define MFMAI8(a, b, c) __builtin_amdgcn_mfma_i32_16x16x64_i8((a), (b), (c), 0, 0, 0)
#define MFMAF16(a, b, c) __builtin_amdgcn_mfma_f32_16x16x32_f16((a), (b), (c), 0, 0, 0)

__device__ __forceinline__ short8 ldb8(const bf16* p) {
    return *reinterpret_cast<const short8*>(p);
}
__device__ __forceinline__ int lo16(unsigned u) { return (int)(u << 16) >> 16; }
__device__ __forceinline__ int hi16(unsigned u) { return (int)u >> 16; }

// -------------------------------------------------------------------------
// Prep: split X and W into f16 hi/lo pairs (Dekker, scaled by 512; exact
// power-of-2 scales), cast Wp to bf16.
// -------------------------------------------------------------------------
__global__ __launch_bounds__(256) void k_prep(
    const float* __restrict__ X, const float* __restrict__ W, const float* __restrict__ Wp,
    _Float16* __restrict__ Xh, _Float16* __restrict__ Xl,
    _Float16* __restrict__ Wh, _Float16* __restrict__ Wl, bf16* __restrict__ Wpb)
{
    const int NX = 4096 * 512, NW = 1536 * 512, NP = 512 * 512;
    for (int i = blockIdx.x * 256 + threadIdx.x; i < NX + NW + NP; i += gridDim.x * 256) {
        if (i < NX) {
            const float v = X[i] * 512.0f;
            const _Float16 h = (_Float16)v;
            Xh[i] = h;
            Xl[i] = (_Float16)((v - (float)h) * 2048.0f);
        } else if (i < NX + NW) {
            const int j = i - NX;
            const float v = W[j] * 512.0f;
            const _Float16 h = (_Float16)v;
            Wh[j] = h;
            Wl[j] = (_Float16)((v - (float)h) * 2048.0f);
        } else {
            const int j = i - NX - NW;
            Wpb[j] = __float2bfloat16(Wp[j]);
        }
    }
}

// -------------------------------------------------------------------------
// Kernel 1: QKV via f16-split MFMA. Round-9 change: fully-unrolled K loop
// with explicit depth-2 double-buffered fragments (r8 PMC: MfmaUtil 7.8%,
// VALUBusy 6%, occupancy 30% => dependent-load latency-bound; compiler
// was not pipelining across kc iterations).
// MFMA order per accumulator is identical to r8 (bit-exact results).
// -------------------------------------------------------------------------
__global__ __launch_bounds__(256, 3) void k_qkv_f16(
    const _Float16* __restrict__ Xh, const _Float16* __restrict__ Xl,
    const _Float16* __restrict__ Wh, const _Float16* __restrict__ Wl,
    const float* __restrict__ bq,
    const float* __restrict__ qvm, const float* __restrict__ kvm, const float* __restrict__ vvm,
    const int* __restrict__ qac, const int* __restrict__ kac, const int* __restrict__ vac,
    int8_t* __restrict__ Q2, int8_t* __restrict__ K2c,
    int8_t* __restrict__ VsT, int8_t* __restrict__ VaT)
{
    const int tid = threadIdx.x;
    const int w = tid >> 6, lane = tid & 63, lo = lane & 15, hi = lane >> 4;
    const int wr = w >> 1, wc = w & 1;
    const int r0 = blockIdx.y * 64 + wr * 32;      // 32 rows for this wave
    const int c0 = blockIdx.x * 128 + wc * 64;     // 64 cols for this wave

    f32x4 hh[2][4] = {};
    f32x4 md[2][4] = {};

    const _Float16* xhp = Xh + (size_t)(r0 + lo) * 512 + hi * 8;
    const _Float16* xlp = Xl + (size_t)(r0 + lo) * 512 + hi * 8;
    const _Float16* whp = Wh + (size_t)(c0 + lo) * 512 + hi * 8;
    const _Float16* wlp = Wl + (size_t)(c0 + lo) * 512 + hi * 8;

    // depth-2 double-buffered fragment pipeline
    fp16x8 fA[2][4], fB[2][8];
    {
        fA[0][0] = *reinterpret_cast<const fp16x8*>(xhp);
        fA[0][1] = *reinterpret_cast<const fp16x8*>(xhp + 16 * 512);
        fA[0][2] = *reinterpret_cast<const fp16x8*>(xlp);
        fA[0][3] = *reinterpret_cast<const fp16x8*>(xlp + 16 * 512);
        #pragma unroll
        for (int j = 0; j < 4; ++j) {
            fB[0][j]     = *reinterpret_cast<const fp16x8*>(whp + j * 16 * 512);
            fB[0][j + 4] = *reinterpret_cast<const fp16x8*>(wlp + j * 16 * 512);
        }
    }
    #pragma unroll
    for (int kc = 0; kc < 16; ++kc) {
        const int cur = kc & 1, nxt = cur ^ 1;
        if (kc < 15) {
            const int ko = (kc + 1) * 32;
            fA[nxt][0] = *reinterpret_cast<const fp16x8*>(xhp + ko);
            fA[nxt][1] = *reinterpret_cast<const fp16x8*>(xhp + ko + 16 * 512);
            fA[nxt][2] = *reinterpret_cast<const fp16x8*>(xlp + ko);
            fA[nxt][3] = *reinterpret_cast<const fp16x8*>(xlp + ko + 16 * 512);
            #pragma unroll
            for (int j = 0; j < 4; ++j) {
                fB[nxt][j]     = *reinterpret_cast<const fp16x8*>(whp + ko + j * 16 * 512);
                fB[nxt][j + 4] = *reinterpret_cast<const fp16x8*>(wlp + ko + j * 16 * 512);
            }
        }
        #pragma unroll
        for (int j = 0; j < 4; ++j) {
            hh[0][j] = MFMAF16(fA[cur][0], fB[cur][j], hh[0][j]);
            hh[1][j] = MFMAF16(fA[cur][1], fB[cur][j], hh[1][j]);
            md[0][j] = MFMAF16(fA[cur][0], fB[cur][j + 4], md[0][j]);
            md[0][j] = MFMAF16(fA[cur][2], fB[cur][j], md[0][j]);
            md[1][j] = MFMAF16(fA[cur][1], fB[cur][j + 4], md[1][j]);
            md[1][j] = MFMAF16(fA[cur][3], fB[cur][j], md[1][j]);
        }
    }

    const int sel = (unsigned)c0 >> 9;
    const float* VM = (sel == 0) ? qvm : (sel == 1) ? kvm : vvm;
    const int*   AC = (sel == 0) ? qac : (sel == 1) ? kac : vac;

    #pragma unroll
    for (int i = 0; i < 2; ++i) {
        const int rowb = r0 + i * 16 + hi * 4;
        const int b = rowb >> 10, nb = rowb & 1023;
        #pragma unroll
        for (int j = 0; j < 4; ++j) {
            const int c = c0 + j * 16 + lo;
            const int ch = c & 511;
            const int hh_ = ch >> 6, d = ch & 63;
            const int bh = b * 8 + hh_;
            const float bcol = bq[c];
            int sp[4], a4[4];
            #pragma unroll
            for (int r = 0; r < 4; ++r) {
                const size_t gi = (size_t)(bh * 1024 + nb + r) * 64 + d;
                const float vm = VM[gi];
                const int a0 = AC[gi];
                const float val = fmaf(md[i][j][r], 0x1p-11f, hh[i][j][r]) * 0x1p-18f;
                const float v_ = vm + (val + bcol);
                int s = ((v_ >= 1.0f) && (a0 < 7)) ? 1 : 0;
                if (v_ < 0.0f) s -= 1;
                sp[r] = s; a4[r] = a0;
            }
            if (sel == 2) {
                uchar4 us, ua;
                us.x = (uint8_t)sp[0]; us.y = (uint8_t)sp[1]; us.z = (uint8_t)sp[2]; us.w = (uint8_t)sp[3];
                ua.x = (uint8_t)(a4[0] + sp[0]); ua.y = (uint8_t)(a4[1] + sp[1]);
                ua.z = (uint8_t)(a4[2] + sp[2]); ua.w = (uint8_t)(a4[3] + sp[3]);
                const size_t vi = (size_t)(bh * 64 + d) * 1024 + nb;   // nb % 4 == 0
                *reinterpret_cast<uchar4*>(VsT + vi) = us;             // Vs  = sp
                *reinterpret_cast<uchar4*>(VaT + vi) = ua;             // Vsum = sp+acc
            } else {
                int8_t* base = ((sel == 0) ? Q2 : K2c) + (size_t)(bh * 1024 + nb) * 128 + d;
                #pragma unroll
                for (int r = 0; r < 4; ++r) {
                    const int v0 = (sel == 0) ? a4[r] + sp[r] : sp[r];
                    const int v1 = (sel == 0) ? sp[r]         : a4[r];
                    base[r * 128]      = (int8_t)v0;
                    base[r * 128 + 64] = (int8_t)v1;
                }
            }
        }
    }
}

// -------------------------------------------------------------------------
// AV0 partials: AV0[hk][bh][n][d] = sum_{k in half hk} aac[bh][n][k]*Vs[bh][d][k]
// 2-way K-split -> grid (16,32,2) = 1024 blocks (4/CU). Exact i32.
// -------------------------------------------------------------------------
__global__ __launch_bounds__(256, 4) void k_av0(
    const int* __restrict__ aac, const int8_t* __restrict__ VsT,
    uint8_t* __restrict__ aac8, int* __restrict__ AV0)
{
    const int w = threadIdx.x >> 6, lane = threadIdx.x & 63;
    const int lo = lane & 15, hi = lane >> 4;
    const int bh = blockIdx.y;
    const int hk = blockIdx.z;                 // K half: k in [hk*512, hk*512+512)
    const int ko0 = hk * 512;
    const int row = blockIdx.x * 64 + w * 16 + lo;
    const size_t arow = ((size_t)bh * 1024 + row) * 1024;

    int4 buf[2][4];
    {
        const int4* ap0 = reinterpret_cast<const int4*>(aac + arow + ko0 + hi * 16);
        const int4* ap1 = reinterpret_cast<const int4*>(aac + arow + ko0 + 64 + hi * 16);
        #pragma unroll
        for (int j = 0; j < 4; ++j) { buf[0][j] = ap0[j]; buf[1][j] = ap1[j]; }
    }

    int4v acc[4] = {{0,0,0,0},{0,0,0,0},{0,0,0,0},{0,0,0,0}};
    #pragma unroll
    for (int tt = 0; tt < 8; ++tt) {
        int4 c[4];
        #pragma unroll
        for (int j = 0; j < 4; ++j) c[j] = buf[tt & 1][j];
        if (tt < 6) {
            const int4* ap = reinterpret_cast<const int4*>(aac + arow + ko0 + (tt + 2) * 64 + hi * 16);
            #pragma unroll
            for (int j = 0; j < 4; ++j) buf[tt & 1][j] = ap[j];
        }
        int4v af;
        af[0] = (int)(unsigned)(c[0].x | (c[0].y << 8) | (c[0].z << 16) | (c[0].w << 24));
        af[1] = (int)(unsigned)(c[1].x | (c[1].y << 8) | (c[1].z << 16) | (c[1].w << 24));
        af[2] = (int)(unsigned)(c[2].x | (c[2].y << 8) | (c[2].z << 16) | (c[2].w << 24));
        af[3] = (int)(unsigned)(c[3].x | (c[3].y << 8) | (c[3].z << 16) | (c[3].w << 24));
        *reinterpret_cast<int4v*>(aac8 + arow + ko0 + tt * 64 + hi * 16) = af;
        #pragma unroll
        for (int dt = 0; dt < 4; ++dt) {
            const int4v bf = *reinterpret_cast<const int4v*>(
                VsT + ((size_t)(bh * 64 + dt * 16 + lo)) * 1024 + ko0 + tt * 64 + hi * 16);
            acc[dt] = MFMAI8(af, bf, acc[dt]);
        }
    }
    int* outp = AV0 + (size_t)hk * 32 * 1024 * 64;
    #pragma unroll
    for (int dt = 0; dt < 4; ++dt)
        #pragma unroll
        for (int r = 0; r < 4; ++r)
            outp[((size_t)bh * 1024 + blockIdx.x * 64 + w * 16 + hi * 4 + r) * 64 + dt * 16 + lo] = acc[dt][r];
}

// -------------------------------------------------------------------------
// Kernel 2 (v8, unchanged): 16 rows/block, i16-packed register scores,
// aac8 gate stream, sp-only P LDS (16.9 KB), PV = sp@Vsum + (AV0a+AV0b).
// __launch_bounds__(256,4): 128-reg unified budget -> no spill.
// -------------------------------------------------------------------------
__global__ __launch_bounds__(256, 4) void k_attn(
    const int8_t* __restrict__ Q2, const int8_t* __restrict__ K2c,
    const float* __restrict__ avm, const uint8_t* __restrict__ aac8,
    const int8_t* __restrict__ Vsum, const int* __restrict__ AV0,
    bf16* __restrict__ O2)
{
    __shared__ alignas(16) char Sc[16896];
    int*   const maxb = (int*)(Sc + 16384);     // [4][16]
    float* const sumb = (float*)(Sc + 16640);   // [4][16]
    const int w = threadIdx.x >> 6, lane = threadIdx.x & 63;
    const int lo = lane & 15, hi = lane >> 4;
    const int bh = blockIdx.z * 8 + blockIdx.y;
    const int n0 = blockIdx.x * 16;

    // ---- Phase 1: swapped scores -> i16-packed registers (K depth-2) ----
    unsigned pA[16][2];
    {
        const int8_t* qb = Q2 + ((size_t)(bh * 1024 + n0 + lo)) * 128 + hi * 16;
        const int4v qa0 = *reinterpret_cast<const int4v*>(qb);
        const int4v qa1 = *reinterpret_cast<const int4v*>(qb + 64);
        const int8_t* kbp = K2c + ((size_t)(bh * 1024 + w * 256 + lo)) * 128 + hi * 16;
        int4v b0[2], b1[2];
        b0[0] = *reinterpret_cast<const int4v*>(kbp);
        b1[0] = *reinterpret_cast<const int4v*>(kbp + 64);
        b0[1] = *reinterpret_cast<const int4v*>(kbp + 2048);
        b1[1] = *reinterpret_cast<const int4v*>(kbp + 2048 + 64);
        #pragma unroll
        for (int t = 0; t < 16; ++t) {
            const int4v c0f = b0[t & 1], c1f = b1[t & 1];
            if (t < 14) {
                const int8_t* np = kbp + (t + 2) * 2048;
                b0[t & 1] = *reinterpret_cast<const int4v*>(np);
                b1[t & 1] = *reinterpret_cast<const int4v*>(np + 64);
            }
            int4v s = {0, 0, 0, 0};
            s = MFMAI8(c0f, qa0, s);
            s = MFMAI8(c1f, qa1, s);
            pA[t][0] = (s[0] & 0xFFFF) | ((unsigned)s[1] << 16);   // |s|<=960 fits i16
            pA[t][1] = (s[2] & 0xFFFF) | ((unsigned)s[3] << 16);
        }
    }

    // ---- burst-4 avm/aac8 prefetch (latency covered by reductions) ----
    const float*   vmp = avm  + ((size_t)(bh * 1024 + n0 + lo)) * 1024 + w * 256 + hi * 4;
    const uint8_t* acp = aac8 + ((size_t)(bh * 1024 + n0 + lo)) * 1024 + w * 256 + hi * 4;
    float4 vmr[4]; uchar4 acr[4];
#define PF(u) { vmr[(u)&3] = *reinterpret_cast<const float4*>(vmp + (u)*16); \
                acr[(u)&3] = *reinterpret_cast<const uchar4*>(acp + (u)*16); }
    PF(0) PF(1) PF(2) PF(3)

    // ---- Phase 2: row max (exact int), then sum of exp2 ----
    int mxi = -32768;
    #pragma unroll
    for (int t = 0; t < 16; ++t) {
        mxi = max(mxi, max(max(lo16(pA[t][0]), hi16(pA[t][0])),
                           max(lo16(pA[t][1]), hi16(pA[t][1]))));
    }
    mxi = max(mxi, __shfl_xor(mxi, 16));
    mxi = max(mxi, __shfl_xor(mxi, 32));
    if (lane < 16) maxb[w * 16 + lo] = mxi;
    __syncthreads();
    const int M = max(max(maxb[lo], maxb[16 + lo]), max(maxb[32 + lo], maxb[48 + lo]));

    const float kls = 0.18033688011112042f;   // 0.125 * log2(e)
    float sum = 0.f;
    #pragma unroll
    for (int t = 0; t < 16; ++t) {
        sum += exp2f(kls * (float)(lo16(pA[t][0]) - M));
        sum += exp2f(kls * (float)(hi16(pA[t][0]) - M));
        sum += exp2f(kls * (float)(lo16(pA[t][1]) - M));
        sum += exp2f(kls * (float)(hi16(pA[t][1]) - M));
    }
    sum += __shfl_xor(sum, 16);
    sum += __shfl_xor(sum, 32);
    if (lane < 16) sumb[w * 16 + lo] = sum;
    __syncthreads();
    const float rsum = 7.0f / ((sumb[lo] + sumb[16 + lo]) + (sumb[32 + lo] + sumb[48 + lo]));

    // ---- Phase 3: attn-IF, sp-only int8 pack, rolling depth-4 stream ----
    #pragma unroll
    for (int u = 0; u < 16; ++u) {
        const float4 vm = vmr[u & 3];
        const uchar4 a8 = acr[u & 3];
        if (u < 12) PF(u + 4)
        const int sv[4] = { lo16(pA[u][0]), hi16(pA[u][0]), lo16(pA[u][1]), hi16(pA[u][1]) };
        const float vr[4] = { vm.x, vm.y, vm.z, vm.w };
        const int   ar[4] = { a8.x, a8.y, a8.z, a8.w };
        unsigned pk = 0;
        #pragma unroll
        for (int i = 0; i < 4; ++i) {
            const float e_ = exp2f(kls * (float)(sv[i] - M));
            const float p7 = e_ * rsum;
            const float v_ = (vr[i] + 0.2f) + p7;   // > 0 always (avm>=0, p7>0)
            const unsigned sp = ((v_ >= 1.0f) && (ar[i] < 7)) ? 1u : 0u;
            pk |= sp << (8 * i);
        }
        char* pb = Sc + lo * 1024 + ((w * 256 + u * 16 + hi * 4) ^ ((lo & 7) << 4));
        *reinterpret_cast<unsigned*>(pb) = pk;
    }
#undef PF
    __syncthreads();   // P fully written

    // ---- Phase 4: PV = sp @ Vsum (i8 MFMA) + AV0a + AV0b, after-IF ----
    {
        const int d0 = w * 16;
        const int* avp = AV0 + ((size_t)(bh * 1024 + n0 + hi * 4)) * 64 + d0 + lo;
        int av[4];
        #pragma unroll
        for (int r = 0; r < 4; ++r)
            av[r] = avp[(size_t)r * 64] + avp[(size_t)r * 64 + (size_t)32 * 1024 * 64];

        const int8_t* vp = Vsum + ((size_t)(bh * 64 + d0 + lo)) * 1024 + hi * 16;
        int4v nv0 = *reinterpret_cast<const int4v*>(vp);
        int4v nv1 = *reinterpret_cast<const int4v*>(vp + 64);
        int4v acc = {0, 0, 0, 0};
        #pragma unroll
        for (int tt = 0; tt < 16; ++tt) {
            const int4v cv = (tt & 1) ? nv1 : nv0;
            if (tt < 14) {
                if (tt & 1) nv1 = *reinterpret_cast<const int4v*>(vp + (tt + 2) * 64);
                else        nv0 = *reinterpret_cast<const int4v*>(vp + (tt + 2) * 64);
            }
            const int ko = tt * 64 + hi * 16;
            const int4v a1 = *reinterpret_cast<const int4v*>(Sc + lo * 1024 + (ko ^ ((lo & 7) << 4)));
            acc = MFMAI8(a1, cv, acc);
        }
        #pragma unroll
        for (int r = 0; r < 4; ++r) {
            const int o = acc[r] + av[r];           // exact integer
            const float f = (float)o;
            const float o2 = (f >= 0.5f ? 1.f : 0.f) - (f < -0.5f ? 1.f : 0.f);
            const int n = n0 + hi * 4 + r;
            O2[((size_t)(blockIdx.z * 1024 + n)) * 512 + blockIdx.y * 64 + d0 + lo] = __float2bfloat16(o2);
        }
    }
}

// -------------------------------------------------------------------------
// Kernel 3: Y = O2 @ Wp^T + b_proj. Round-9: depth-2 fragment dbuf
// (same latency-hiding pattern as k_qkv; MFMA order unchanged).
// -------------------------------------------------------------------------
__global__ __launch_bounds__(256) void k_proj(
    const bf16* __restrict__ O2, const bf16* __restrict__ W, const float* __restrict__ bias,
    float* __restrict__ Y)
{
    const int w = threadIdx.x >> 6, lane = threadIdx.x & 63;
    const int lo = lane & 15, hi = lane >> 4;
    const int r0 = blockIdx.y * 16;
    const int c0 = blockIdx.x * 256 + w * 64;

    f32x4 acc[4] = {{0.f,0.f,0.f,0.f},{0.f,0.f,0.f,0.f},{0.f,0.f,0.f,0.f},{0.f,0.f,0.f,0.f}};
    const bf16* op  = O2 + (size_t)(r0 + lo) * 512 + hi * 8;
    const bf16* wp0 = W + (size_t)(c0 + lo) * 512 + hi * 8;

    short8 a2[2], b2[2][4];
    a2[0] = ldb8(op);
    #pragma unroll
    for (int t = 0; t < 4; ++t) b2[0][t] = ldb8(wp0 + t * 16 * 512);

    #pragma unroll
    for (int kb = 0; kb < 16; ++kb) {
        const int cur = kb & 1, nxt = cur ^ 1;
        if (kb < 15) {
            a2[nxt] = ldb8(op + (kb + 1) * 32);
            #pragma unroll
            for (int t = 0; t < 4; ++t)
                b2[nxt][t] = ldb8(wp0 + t * 16 * 512 + (kb + 1) * 32);
        }
        #pragma unroll
        for (int t = 0; t < 4; ++t)
            acc[t] = MFMA16(a2[cur], b2[cur][t], acc[t]);
    }
    #pragma unroll
    for (int t = 0; t < 4; ++t) {
        const int col = c0 + t * 16 + lo;
        const float bcol = bias[col];
        #pragma unroll
        for (int r = 0; r < 4; ++r) {
            const int rr = r0 + hi * 4 + r;
            Y[(size_t)rr * 512 + col] = acc[t][r] + bcol;
        }
    }
}

// -------------------------------------------------------------------------
extern "C" void kernel_launch(void* const* d_in, const int* in_sizes, int n_in,
                              void* d_out, int out_size, void* d_ws, size_t ws_size,
                              hipStream_t stream)
{
    const float* x     = (const float*)d_in[0];
    const float* wqkv  = (const float*)d_in[1];
    const float* bqkv  = (const float*)d_in[2];
    const float* wproj = (const float*)d_in[3];
    const float* bproj = (const float*)d_in[4];
    const float* qvm   = (const float*)d_in[5];
    const float* kvm   = (const float*)d_in[6];
    const float* vvm   = (const float*)d_in[7];
    const float* avm   = (const float*)d_in[8];
    const int*   qac   = (const int*)d_in[9];
    const int*   kac   = (const int*)d_in[10];
    const int*   vac   = (const int*)d_in[11];
    const int*   aac   = (const int*)d_in[12];

    char* p = (char*)d_ws;
    int8_t*   Q2   = (int8_t*)p;   p += (size_t)32 * 1024 * 128;       // 4 MB
    int8_t*   K2c  = (int8_t*)p;   p += (size_t)32 * 1024 * 128;       // 4 MB
    int8_t*   VsT  = (int8_t*)p;   p += (size_t)32 * 64 * 1024;        // 2 MB  Vs (sp)
    int8_t*   VaT  = (int8_t*)p;   p += (size_t)32 * 64 * 1024;        // 2 MB  Vsum
    bf16*     O2   = (bf16*)p;     p += (size_t)4096 * 512 * 2;        // 4 MB
    bf16*     Wpb  = (bf16*)p;     p += (size_t)512 * 512 * 2;         // 0.5 MB
    _Float16* Xh   = (_Float16*)p; p += (size_t)4096 * 512 * 2;        // 4 MB
    _Float16* Xl   = (_Float16*)p; p += (size_t)4096 * 512 * 2;        // 4 MB
    _Float16* Wh   = (_Float16*)p; p += (size_t)1536 * 512 * 2;        // 1.5 MB
    _Float16* Wl   = (_Float16*)p; p += (size_t)1536 * 512 * 2;        // 1.5 MB
    uint8_t*  aac8 = (uint8_t*)p;  p += (size_t)32 * 1024 * 1024;      // 32 MB
    int*      AV0  = (int*)p;      p += (size_t)2 * 32 * 1024 * 64 * 4;// 16 MB (2 K-halves)

    k_prep<<<dim3(2048), 256, 0, stream>>>(x, wqkv, wproj, Xh, Xl, Wh, Wl, Wpb);
    k_qkv_f16<<<dim3(12, 64), 256, 0, stream>>>(Xh, Xl, Wh, Wl, bqkv, qvm, kvm, vvm,
                                                qac, kac, vac, Q2, K2c, VsT, VaT);
    k_av0<<<dim3(16, 32, 2), 256, 0, stream>>>(aac, VsT, aac8, AV0);
    k_attn<<<dim3(64, 8, 4), 256, 0, stream>>>(Q2, K2c, avm, aac8, VaT, AV0, O2);
    k_proj<<<dim3(2, 256), 256, 0, stream>>>(O2, Wpb, bproj, (float*)d_out);
}

// Round 10
// 455.954 us; speedup vs baseline: 1.0961x; 1.0961x over previous
//
#include <hip/hip_runtime.h>
#include <hip/hip_bf16.h>
#include <cstdint>

typedef short short8 __attribute__((ext_vector_type(8)));
typedef float f32x4 __attribute__((ext_vector_type(4)));
typedef int   int4v __attribute__((ext_vector_type(4)));
typedef _Float16 fp16x8 __attribute__((ext_vector_type(8)));

using bf16 = __hip_bfloat16;

#define MFMA16(a, b, c) __builtin_amdgcn_mfma_f32_16x16x32_bf16((a), (b), (c), 0, 0, 0)
#define MFMAI8(a, b, c) __builtin_amdgcn_mfma_i32_16x16x64_i8((a), (b), (c), 0, 0, 0)
#define MFMAF16(a, b, c) __builtin_amdgcn_mfma_f32_16x16x32_f16((a), (b), (c), 0, 0, 0)

__device__ __forceinline__ short8 ldb8(const bf16* p) {
    return *reinterpret_cast<const short8*>(p);
}
__device__ __forceinline__ int lo16(unsigned u) { return (int)(u << 16) >> 16; }
__device__ __forceinline__ int hi16(unsigned u) { return (int)u >> 16; }

// -------------------------------------------------------------------------
// Prep: split X and W into f16 hi/lo pairs (Dekker, scaled by 512; exact
// power-of-2 scales), cast Wp to bf16.
// -------------------------------------------------------------------------
__global__ __launch_bounds__(256) void k_prep(
    const float* __restrict__ X, const float* __restrict__ W, const float* __restrict__ Wp,
    _Float16* __restrict__ Xh, _Float16* __restrict__ Xl,
    _Float16* __restrict__ Wh, _Float16* __restrict__ Wl, bf16* __restrict__ Wpb)
{
    const int NX = 4096 * 512, NW = 1536 * 512, NP = 512 * 512;
    for (int i = blockIdx.x * 256 + threadIdx.x; i < NX + NW + NP; i += gridDim.x * 256) {
        if (i < NX) {
            const float v = X[i] * 512.0f;
            const _Float16 h = (_Float16)v;
            Xh[i] = h;
            Xl[i] = (_Float16)((v - (float)h) * 2048.0f);
        } else if (i < NX + NW) {
            const int j = i - NX;
            const float v = W[j] * 512.0f;
            const _Float16 h = (_Float16)v;
            Wh[j] = h;
            Wl[j] = (_Float16)((v - (float)h) * 2048.0f);
        } else {
            const int j = i - NX - NW;
            Wpb[j] = __float2bfloat16(Wp[j]);
        }
    }
}

// -------------------------------------------------------------------------
// Kernel 1 (r10): QKV via f16-split MFMA with LDS-staged operands.
// r9 PMC: direct-global frag loads serialized at L2/L3 latency (~14k cyc
// per K-iter, MfmaUtil 7.7%, FETCH 8x X size from cross-XCD refetch).
// Fix: per 32-K chunk, 256 threads reg-stage 6x16B -> ds_write 24KB tile
// -> ds_read_b128 frags (lane-linear, conflict-uniform). Next chunk's
// global loads issue under compute. MFMA order unchanged (bit-exact).
// -------------------------------------------------------------------------
__global__ __launch_bounds__(256, 3) void k_qkv_f16(
    const _Float16* __restrict__ Xh, const _Float16* __restrict__ Xl,
    const _Float16* __restrict__ Wh, const _Float16* __restrict__ Wl,
    const float* __restrict__ bq,
    const float* __restrict__ qvm, const float* __restrict__ kvm, const float* __restrict__ vvm,
    const int* __restrict__ qac, const int* __restrict__ kac, const int* __restrict__ vac,
    int8_t* __restrict__ Q2, int8_t* __restrict__ K2c,
    int8_t* __restrict__ VsT, int8_t* __restrict__ VaT)
{
    __shared__ alignas(16) _Float16 XhL[64 * 32];    // [row][k] 64B rows
    __shared__ alignas(16) _Float16 XlL[64 * 32];
    __shared__ alignas(16) _Float16 WhL[128 * 32];   // [col][k]
    __shared__ alignas(16) _Float16 WlL[128 * 32];

    const int tid = threadIdx.x;
    const int w = tid >> 6, lane = tid & 63, lo = lane & 15, hi = lane >> 4;
    const int wr = w >> 1, wc = w & 1;
    const int r0w = blockIdx.y * 64 + wr * 32;     // wave's 32 rows
    const int c0w = blockIdx.x * 128 + wc * 64;    // wave's 64 cols

    // staging: thread t owns X slot t (row=t>>2, k8=t&3), W slots t and t+256
    const int srow = tid >> 2, sk8 = tid & 3;
    const _Float16* gxh  = Xh + (size_t)(blockIdx.y * 64 + srow) * 512 + sk8 * 8;
    const _Float16* gxl  = Xl + (size_t)(blockIdx.y * 64 + srow) * 512 + sk8 * 8;
    const _Float16* gw0h = Wh + (size_t)(blockIdx.x * 128 + srow) * 512 + sk8 * 8;
    const _Float16* gw1h = Wh + (size_t)(blockIdx.x * 128 + 64 + srow) * 512 + sk8 * 8;
    const _Float16* gw0l = Wl + (size_t)(blockIdx.x * 128 + srow) * 512 + sk8 * 8;
    const _Float16* gw1l = Wl + (size_t)(blockIdx.x * 128 + 64 + srow) * 512 + sk8 * 8;

    float4 sxh, sxl, sw0h, sw1h, sw0l, sw1l;
#define QISSUE(kc) { const int off_ = (kc) * 32; \
    sxh  = *reinterpret_cast<const float4*>(gxh  + off_); \
    sxl  = *reinterpret_cast<const float4*>(gxl  + off_); \
    sw0h = *reinterpret_cast<const float4*>(gw0h + off_); \
    sw1h = *reinterpret_cast<const float4*>(gw1h + off_); \
    sw0l = *reinterpret_cast<const float4*>(gw0l + off_); \
    sw1l = *reinterpret_cast<const float4*>(gw1l + off_); }

    QISSUE(0)

    f32x4 hh[2][4] = {};
    f32x4 md[2][4] = {};

    for (int kc = 0; kc < 16; ++kc) {
        __syncthreads();   // previous compute done -> LDS reusable
        *reinterpret_cast<float4*>(XhL + tid * 8)         = sxh;
        *reinterpret_cast<float4*>(XlL + tid * 8)         = sxl;
        *reinterpret_cast<float4*>(WhL + tid * 8)         = sw0h;
        *reinterpret_cast<float4*>(WhL + (tid + 256) * 8) = sw1h;
        *reinterpret_cast<float4*>(WlL + tid * 8)         = sw0l;
        *reinterpret_cast<float4*>(WlL + (tid + 256) * 8) = sw1l;
        if (kc < 15) QISSUE(kc + 1);   // next chunk's HBM latency hides under compute
        __syncthreads();   // LDS writes visible

        const fp16x8 Ah0 = *reinterpret_cast<const fp16x8*>(XhL + (wr * 32 + lo) * 32 + hi * 8);
        const fp16x8 Ah1 = *reinterpret_cast<const fp16x8*>(XhL + (wr * 32 + 16 + lo) * 32 + hi * 8);
        const fp16x8 Al0 = *reinterpret_cast<const fp16x8*>(XlL + (wr * 32 + lo) * 32 + hi * 8);
        const fp16x8 Al1 = *reinterpret_cast<const fp16x8*>(XlL + (wr * 32 + 16 + lo) * 32 + hi * 8);
        fp16x8 Bh[4], Bl[4];
        #pragma unroll
        for (int j = 0; j < 4; ++j) {
            const int cl = (wc * 64 + j * 16 + lo) * 32 + hi * 8;
            Bh[j] = *reinterpret_cast<const fp16x8*>(WhL + cl);
            Bl[j] = *reinterpret_cast<const fp16x8*>(WlL + cl);
        }
        #pragma unroll
        for (int j = 0; j < 4; ++j) {
            hh[0][j] = MFMAF16(Ah0, Bh[j], hh[0][j]);
            hh[1][j] = MFMAF16(Ah1, Bh[j], hh[1][j]);
            md[0][j] = MFMAF16(Ah0, Bl[j], md[0][j]);
            md[0][j] = MFMAF16(Al0, Bh[j], md[0][j]);
            md[1][j] = MFMAF16(Ah1, Bl[j], md[1][j]);
            md[1][j] = MFMAF16(Al1, Bh[j], md[1][j]);
        }
    }
#undef QISSUE

    const int sel = (unsigned)c0w >> 9;
    const float* VM = (sel == 0) ? qvm : (sel == 1) ? kvm : vvm;
    const int*   AC = (sel == 0) ? qac : (sel == 1) ? kac : vac;

    #pragma unroll
    for (int i = 0; i < 2; ++i) {
        const int rowb = r0w + i * 16 + hi * 4;
        const int b = rowb >> 10, nb = rowb & 1023;
        #pragma unroll
        for (int j = 0; j < 4; ++j) {
            const int c = c0w + j * 16 + lo;
            const int ch = c & 511;
            const int hh_ = ch >> 6, d = ch & 63;
            const int bh = b * 8 + hh_;
            const float bcol = bq[c];
            int sp[4], a4[4];
            #pragma unroll
            for (int r = 0; r < 4; ++r) {
                const size_t gi = (size_t)(bh * 1024 + nb + r) * 64 + d;
                const float vm = VM[gi];
                const int a0 = AC[gi];
                const float val = fmaf(md[i][j][r], 0x1p-11f, hh[i][j][r]) * 0x1p-18f;
                const float v_ = vm + (val + bcol);
                int s = ((v_ >= 1.0f) && (a0 < 7)) ? 1 : 0;
                if (v_ < 0.0f) s -= 1;
                sp[r] = s; a4[r] = a0;
            }
            if (sel == 2) {
                uchar4 us, ua;
                us.x = (uint8_t)sp[0]; us.y = (uint8_t)sp[1]; us.z = (uint8_t)sp[2]; us.w = (uint8_t)sp[3];
                ua.x = (uint8_t)(a4[0] + sp[0]); ua.y = (uint8_t)(a4[1] + sp[1]);
                ua.z = (uint8_t)(a4[2] + sp[2]); ua.w = (uint8_t)(a4[3] + sp[3]);
                const size_t vi = (size_t)(bh * 64 + d) * 1024 + nb;   // nb % 4 == 0
                *reinterpret_cast<uchar4*>(VsT + vi) = us;             // Vs  = sp
                *reinterpret_cast<uchar4*>(VaT + vi) = ua;             // Vsum = sp+acc
            } else {
                int8_t* base = ((sel == 0) ? Q2 : K2c) + (size_t)(bh * 1024 + nb) * 128 + d;
                #pragma unroll
                for (int r = 0; r < 4; ++r) {
                    const int v0 = (sel == 0) ? a4[r] + sp[r] : sp[r];
                    const int v1 = (sel == 0) ? sp[r]         : a4[r];
                    base[r * 128]      = (int8_t)v0;
                    base[r * 128 + 64] = (int8_t)v1;
                }
            }
        }
    }
}

// -------------------------------------------------------------------------
// AV0 partials: AV0[hk][bh][n][d] = sum_{k in half hk} aac[bh][n][k]*Vs[bh][d][k]
// 2-way K-split -> grid (16,32,2) = 1024 blocks (4/CU). Exact i32.
// -------------------------------------------------------------------------
__global__ __launch_bounds__(256, 4) void k_av0(
    const int* __restrict__ aac, const int8_t* __restrict__ VsT,
    uint8_t* __restrict__ aac8, int* __restrict__ AV0)
{
    const int w = threadIdx.x >> 6, lane = threadIdx.x & 63;
    const int lo = lane & 15, hi = lane >> 4;
    const int bh = blockIdx.y;
    const int hk = blockIdx.z;                 // K half: k in [hk*512, hk*512+512)
    const int ko0 = hk * 512;
    const int row = blockIdx.x * 64 + w * 16 + lo;
    const size_t arow = ((size_t)bh * 1024 + row) * 1024;

    int4 buf[2][4];
    {
        const int4* ap0 = reinterpret_cast<const int4*>(aac + arow + ko0 + hi * 16);
        const int4* ap1 = reinterpret_cast<const int4*>(aac + arow + ko0 + 64 + hi * 16);
        #pragma unroll
        for (int j = 0; j < 4; ++j) { buf[0][j] = ap0[j]; buf[1][j] = ap1[j]; }
    }

    int4v acc[4] = {{0,0,0,0},{0,0,0,0},{0,0,0,0},{0,0,0,0}};
    #pragma unroll
    for (int tt = 0; tt < 8; ++tt) {
        int4 c[4];
        #pragma unroll
        for (int j = 0; j < 4; ++j) c[j] = buf[tt & 1][j];
        if (tt < 6) {
            const int4* ap = reinterpret_cast<const int4*>(aac + arow + ko0 + (tt + 2) * 64 + hi * 16);
            #pragma unroll
            for (int j = 0; j < 4; ++j) buf[tt & 1][j] = ap[j];
        }
        int4v af;
        af[0] = (int)(unsigned)(c[0].x | (c[0].y << 8) | (c[0].z << 16) | (c[0].w << 24));
        af[1] = (int)(unsigned)(c[1].x | (c[1].y << 8) | (c[1].z << 16) | (c[1].w << 24));
        af[2] = (int)(unsigned)(c[2].x | (c[2].y << 8) | (c[2].z << 16) | (c[2].w << 24));
        af[3] = (int)(unsigned)(c[3].x | (c[3].y << 8) | (c[3].z << 16) | (c[3].w << 24));
        *reinterpret_cast<int4v*>(aac8 + arow + ko0 + tt * 64 + hi * 16) = af;
        #pragma unroll
        for (int dt = 0; dt < 4; ++dt) {
            const int4v bf = *reinterpret_cast<const int4v*>(
                VsT + ((size_t)(bh * 64 + dt * 16 + lo)) * 1024 + ko0 + tt * 64 + hi * 16);
            acc[dt] = MFMAI8(af, bf, acc[dt]);
        }
    }
    int* outp = AV0 + (size_t)hk * 32 * 1024 * 64;
    #pragma unroll
    for (int dt = 0; dt < 4; ++dt)
        #pragma unroll
        for (int r = 0; r < 4; ++r)
            outp[((size_t)bh * 1024 + blockIdx.x * 64 + w * 16 + hi * 4 + r) * 64 + dt * 16 + lo] = acc[dt][r];
}

// -------------------------------------------------------------------------
// Kernel 2 (unchanged): 16 rows/block, i16-packed register scores,
// aac8 gate stream, sp-only P LDS (16.9 KB), PV = sp@Vsum + (AV0a+AV0b).
// -------------------------------------------------------------------------
__global__ __launch_bounds__(256, 4) void k_attn(
    const int8_t* __restrict__ Q2, const int8_t* __restrict__ K2c,
    const float* __restrict__ avm, const uint8_t* __restrict__ aac8,
    const int8_t* __restrict__ Vsum, const int* __restrict__ AV0,
    bf16* __restrict__ O2)
{
    __shared__ alignas(16) char Sc[16896];
    int*   const maxb = (int*)(Sc + 16384);     // [4][16]
    float* const sumb = (float*)(Sc + 16640);   // [4][16]
    const int w = threadIdx.x >> 6, lane = threadIdx.x & 63;
    const int lo = lane & 15, hi = lane >> 4;
    const int bh = blockIdx.z * 8 + blockIdx.y;
    const int n0 = blockIdx.x * 16;

    // ---- Phase 1: swapped scores -> i16-packed registers (K depth-2) ----
    unsigned pA[16][2];
    {
        const int8_t* qb = Q2 + ((size_t)(bh * 1024 + n0 + lo)) * 128 + hi * 16;
        const int4v qa0 = *reinterpret_cast<const int4v*>(qb);
        const int4v qa1 = *reinterpret_cast<const int4v*>(qb + 64);
        const int8_t* kbp = K2c + ((size_t)(bh * 1024 + w * 256 + lo)) * 128 + hi * 16;
        int4v b0[2], b1[2];
        b0[0] = *reinterpret_cast<const int4v*>(kbp);
        b1[0] = *reinterpret_cast<const int4v*>(kbp + 64);
        b0[1] = *reinterpret_cast<const int4v*>(kbp + 2048);
        b1[1] = *reinterpret_cast<const int4v*>(kbp + 2048 + 64);
        #pragma unroll
        for (int t = 0; t < 16; ++t) {
            const int4v c0f = b0[t & 1], c1f = b1[t & 1];
            if (t < 14) {
                const int8_t* np = kbp + (t + 2) * 2048;
                b0[t & 1] = *reinterpret_cast<const int4v*>(np);
                b1[t & 1] = *reinterpret_cast<const int4v*>(np + 64);
            }
            int4v s = {0, 0, 0, 0};
            s = MFMAI8(c0f, qa0, s);
            s = MFMAI8(c1f, qa1, s);
            pA[t][0] = (s[0] & 0xFFFF) | ((unsigned)s[1] << 16);   // |s|<=960 fits i16
            pA[t][1] = (s[2] & 0xFFFF) | ((unsigned)s[3] << 16);
        }
    }

    // ---- burst-4 avm/aac8 prefetch (latency covered by reductions) ----
    const float*   vmp = avm  + ((size_t)(bh * 1024 + n0 + lo)) * 1024 + w * 256 + hi * 4;
    const uint8_t* acp = aac8 + ((size_t)(bh * 1024 + n0 + lo)) * 1024 + w * 256 + hi * 4;
    float4 vmr[4]; uchar4 acr[4];
#define PF(u) { vmr[(u)&3] = *reinterpret_cast<const float4*>(vmp + (u)*16); \
                acr[(u)&3] = *reinterpret_cast<const uchar4*>(acp + (u)*16); }
    PF(0) PF(1) PF(2) PF(3)

    // ---- Phase 2: row max (exact int), then sum of exp2 ----
    int mxi = -32768;
    #pragma unroll
    for (int t = 0; t < 16; ++t) {
        mxi = max(mxi, max(max(lo16(pA[t][0]), hi16(pA[t][0])),
                           max(lo16(pA[t][1]), hi16(pA[t][1]))));
    }
    mxi = max(mxi, __shfl_xor(mxi, 16));
    mxi = max(mxi, __shfl_xor(mxi, 32));
    if (lane < 16) maxb[w * 16 + lo] = mxi;
    __syncthreads();
    const int M = max(max(maxb[lo], maxb[16 + lo]), max(maxb[32 + lo], maxb[48 + lo]));

    const float kls = 0.18033688011112042f;   // 0.125 * log2(e)
    float sum = 0.f;
    #pragma unroll
    for (int t = 0; t < 16; ++t) {
        sum += exp2f(kls * (float)(lo16(pA[t][0]) - M));
        sum += exp2f(kls * (float)(hi16(pA[t][0]) - M));
        sum += exp2f(kls * (float)(lo16(pA[t][1]) - M));
        sum += exp2f(kls * (float)(hi16(pA[t][1]) - M));
    }
    sum += __shfl_xor(sum, 16);
    sum += __shfl_xor(sum, 32);
    if (lane < 16) sumb[w * 16 + lo] = sum;
    __syncthreads();
    const float rsum = 7.0f / ((sumb[lo] + sumb[16 + lo]) + (sumb[32 + lo] + sumb[48 + lo]));

    // ---- Phase 3: attn-IF, sp-only int8 pack, rolling depth-4 stream ----
    #pragma unroll
    for (int u = 0; u < 16; ++u) {
        const float4 vm = vmr[u & 3];
        const uchar4 a8 = acr[u & 3];
        if (u < 12) PF(u + 4)
        const int sv[4] = { lo16(pA[u][0]), hi16(pA[u][0]), lo16(pA[u][1]), hi16(pA[u][1]) };
        const float vr[4] = { vm.x, vm.y, vm.z, vm.w };
        const int   ar[4] = { a8.x, a8.y, a8.z, a8.w };
        unsigned pk = 0;
        #pragma unroll
        for (int i = 0; i < 4; ++i) {
            const float e_ = exp2f(kls * (float)(sv[i] - M));
            const float p7 = e_ * rsum;
            const float v_ = (vr[i] + 0.2f) + p7;   // > 0 always (avm>=0, p7>0)
            const unsigned sp = ((v_ >= 1.0f) && (ar[i] < 7)) ? 1u : 0u;
            pk |= sp << (8 * i);
        }
        char* pb = Sc + lo * 1024 + ((w * 256 + u * 16 + hi * 4) ^ ((lo & 7) << 4));
        *reinterpret_cast<unsigned*>(pb) = pk;
    }
#undef PF
    __syncthreads();   // P fully written

    // ---- Phase 4: PV = sp @ Vsum (i8 MFMA) + AV0a + AV0b, after-IF ----
    {
        const int d0 = w * 16;
        const int* avp = AV0 + ((size_t)(bh * 1024 + n0 + hi * 4)) * 64 + d0 + lo;
        int av[4];
        #pragma unroll
        for (int r = 0; r < 4; ++r)
            av[r] = avp[(size_t)r * 64] + avp[(size_t)r * 64 + (size_t)32 * 1024 * 64];

        const int8_t* vp = Vsum + ((size_t)(bh * 64 + d0 + lo)) * 1024 + hi * 16;
        int4v nv0 = *reinterpret_cast<const int4v*>(vp);
        int4v nv1 = *reinterpret_cast<const int4v*>(vp + 64);
        int4v acc = {0, 0, 0, 0};
        #pragma unroll
        for (int tt = 0; tt < 16; ++tt) {
            const int4v cv = (tt & 1) ? nv1 : nv0;
            if (tt < 14) {
                if (tt & 1) nv1 = *reinterpret_cast<const int4v*>(vp + (tt + 2) * 64);
                else        nv0 = *reinterpret_cast<const int4v*>(vp + (tt + 2) * 64);
            }
            const int ko = tt * 64 + hi * 16;
            const int4v a1 = *reinterpret_cast<const int4v*>(Sc + lo * 1024 + (ko ^ ((lo & 7) << 4)));
            acc = MFMAI8(a1, cv, acc);
        }
        #pragma unroll
        for (int r = 0; r < 4; ++r) {
            const int o = acc[r] + av[r];           // exact integer
            const float f = (float)o;
            const float o2 = (f >= 0.5f ? 1.f : 0.f) - (f < -0.5f ? 1.f : 0.f);
            const int n = n0 + hi * 4 + r;
            O2[((size_t)(blockIdx.z * 1024 + n)) * 512 + blockIdx.y * 64 + d0 + lo] = __float2bfloat16(o2);
        }
    }
}

// -------------------------------------------------------------------------
// Kernel 3: Y = O2 @ Wp^T + b_proj (unchanged from r9).
// -------------------------------------------------------------------------
__global__ __launch_bounds__(256) void k_proj(
    const bf16* __restrict__ O2, const bf16* __restrict__ W, const float* __restrict__ bias,
    float* __restrict__ Y)
{
    const int w = threadIdx.x >> 6, lane = threadIdx.x & 63;
    const int lo = lane & 15, hi = lane >> 4;
    const int r0 = blockIdx.y * 16;
    const int c0 = blockIdx.x * 256 + w * 64;

    f32x4 acc[4] = {{0.f,0.f,0.f,0.f},{0.f,0.f,0.f,0.f},{0.f,0.f,0.f,0.f},{0.f,0.f,0.f,0.f}};
    const bf16* op  = O2 + (size_t)(r0 + lo) * 512 + hi * 8;
    const bf16* wp0 = W + (size_t)(c0 + lo) * 512 + hi * 8;

    short8 a2[2], b2[2][4];
    a2[0] = ldb8(op);
    #pragma unroll
    for (int t = 0; t < 4; ++t) b2[0][t] = ldb8(wp0 + t * 16 * 512);

    #pragma unroll
    for (int kb = 0; kb < 16; ++kb) {
        const int cur = kb & 1, nxt = cur ^ 1;
        if (kb < 15) {
            a2[nxt] = ldb8(op + (kb + 1) * 32);
            #pragma unroll
            for (int t = 0; t < 4; ++t)
                b2[nxt][t] = ldb8(wp0 + t * 16 * 512 + (kb + 1) * 32);
        }
        #pragma unroll
        for (int t = 0; t < 4; ++t)
            acc[t] = MFMA16(a2[cur], b2[cur][t], acc[t]);
    }
    #pragma unroll
    for (int t = 0; t < 4; ++t) {
        const int col = c0 + t * 16 + lo;
        const float bcol = bias[col];
        #pragma unroll
        for (int r = 0; r < 4; ++r) {
            const int rr = r0 + hi * 4 + r;
            Y[(size_t)rr * 512 + col] = acc[t][r] + bcol;
        }
    }
}

// -------------------------------------------------------------------------
extern "C" void kernel_launch(void* const* d_in, const int* in_sizes, int n_in,
                              void* d_out, int out_size, void* d_ws, size_t ws_size,
                              hipStream_t stream)
{
    const float* x     = (const float*)d_in[0];
    const float* wqkv  = (const float*)d_in[1];
    const float* bqkv  = (const float*)d_in[2];
    const float* wproj = (const float*)d_in[3];
    const float* bproj = (const float*)d_in[4];
    const float* qvm   = (const float*)d_in[5];
    const float* kvm   = (const float*)d_in[6];
    const float* vvm   = (const float*)d_in[7];
    const float* avm   = (const float*)d_in[8];
    const int*   qac   = (const int*)d_in[9];
    const int*   kac   = (const int*)d_in[10];
    const int*   vac   = (const int*)d_in[11];
    const int*   aac   = (const int*)d_in[12];

    char* p = (char*)d_ws;
    int8_t*   Q2   = (int8_t*)p;   p += (size_t)32 * 1024 * 128;       // 4 MB
    int8_t*   K2c  = (int8_t*)p;   p += (size_t)32 * 1024 * 128;       // 4 MB
    int8_t*   VsT  = (int8_t*)p;   p += (size_t)32 * 64 * 1024;        // 2 MB  Vs (sp)
    int8_t*   VaT  = (int8_t*)p;   p += (size_t)32 * 64 * 1024;        // 2 MB  Vsum
    bf16*     O2   = (bf16*)p;     p += (size_t)4096 * 512 * 2;        // 4 MB
    bf16*     Wpb  = (bf16*)p;     p += (size_t)512 * 512 * 2;         // 0.5 MB
    _Float16* Xh   = (_Float16*)p; p += (size_t)4096 * 512 * 2;        // 4 MB
    _Float16* Xl   = (_Float16*)p; p += (size_t)4096 * 512 * 2;        // 4 MB
    _Float16* Wh   = (_Float16*)p; p += (size_t)1536 * 512 * 2;        // 1.5 MB
    _Float16* Wl   = (_Float16*)p; p += (size_t)1536 * 512 * 2;        // 1.5 MB
    uint8_t*  aac8 = (uint8_t*)p;  p += (size_t)32 * 1024 * 1024;      // 32 MB
    int*      AV0  = (int*)p;      p += (size_t)2 * 32 * 1024 * 64 * 4;// 16 MB (2 K-halves)

    k_prep<<<dim3(2048), 256, 0, stream>>>(x, wqkv, wproj, Xh, Xl, Wh, Wl, Wpb);
    k_qkv_f16<<<dim3(12, 64), 256, 0, stream>>>(Xh, Xl, Wh, Wl, bqkv, qvm, kvm, vvm,
                                                qac, kac, vac, Q2, K2c, VsT, VaT);
    k_av0<<<dim3(16, 32, 2), 256, 0, stream>>>(aac, VsT, aac8, AV0);
    k_attn<<<dim3(64, 8, 4), 256, 0, stream>>>(Q2, K2c, avm, aac8, VaT, AV0, O2);
    k_proj<<<dim3(2, 256), 256, 0, stream>>>(O2, Wpb, bproj, (float*)d_out);
}